// Round 7
// baseline (201.449 us; speedup 1.0000x reference)
//
#include <hip/hip_runtime.h>

#define SCR 68     // scratch feature stride (f16): 136 B = 34 words -> 2-way banks (free); 8B-aligned ops
#define WRS 65     // staged fp32 weight row stride: breaks bank conflicts in frag-fill

typedef _Float16 f16;
typedef f16  f16x4 __attribute__((ext_vector_type(4)));
typedef f16  f16x8 __attribute__((ext_vector_type(8)));
typedef __fp16 h16x2 __attribute__((ext_vector_type(2)));  // cvt_pkrtz native return type
typedef float f32x4  __attribute__((ext_vector_type(4)));
typedef float f32x16 __attribute__((ext_vector_type(16)));

__device__ __forceinline__ float frcp(float x){
#if __has_builtin(__builtin_amdgcn_rcpf)
    return __builtin_amdgcn_rcpf(x);
#else
    return 1.0f / x;
#endif
}

// ---------- activations (fp32, identical numerics to R4-R6) ----------
__device__ __forceinline__ float act_tanh(float x){
    return 1.0f - 2.0f * frcp(1.0f + __expf(2.0f * x));
}
__device__ __forceinline__ float act_elu(float x){
    float e = __expf(x) - 1.0f;
    return x > 0.0f ? x : e;
}
__device__ __forceinline__ float act_softplus(float x){
    float a = fabsf(x);
    return fmaxf(x, 0.0f) + __logf(1.0f + __expf(-a));
}
__device__ __forceinline__ float act_gauss(float x){
    return __expf(-0.5f * x * x);
}
__device__ __forceinline__ float act_sigmoid(float x){
    return frcp(1.0f + __expf(-x));
}
template<int A> __device__ __forceinline__ float act(float v){
    if constexpr (A == 0) return act_tanh(v);
    else if constexpr (A == 1) return act_elu(v);
    else if constexpr (A == 2) return act_softplus(v);
    else if constexpr (A == 3) return __sinf(v);
    else if constexpr (A == 4) return act_gauss(v);
    else                       return act_sigmoid(v);
}

__device__ __forceinline__ f16x4 pack4(float a, float b, float c, float d){
    h16x2 p0 = __builtin_amdgcn_cvt_pkrtz(a, b);
    h16x2 p1 = __builtin_amdgcn_cvt_pkrtz(c, d);
    f16x4 r;
    r[0] = (f16)p0[0]; r[1] = (f16)p0[1]; r[2] = (f16)p1[0]; r[3] = (f16)p1[1];
    return r;
}
__device__ __forceinline__ f16x8 cat8(f16x4 lo, f16x4 hi){
    return __builtin_shufflevector(lo, hi, 0, 1, 2, 3, 4, 5, 6, 7);
}

#define MFMA32(a, b, c) __builtin_amdgcn_mfma_f32_32x32x16_f16((a), (b), (c), 0, 0, 0)

// one node, one 32-pt tile: acc=bias; acc += W^T @ B (8 MFMAs, 2 m-tiles x 4 k-blocks);
// act; LDS transpose (write C-layout rows, read B-layout k-runs) -> OUT frags
template<int ACTI>
__device__ __forceinline__ void node32(const f16* __restrict__ wr,   // &wfrag[ni][0][0][lane][0]
                                       const float* __restrict__ bs, // &b_s[ni][0]
                                       const int hf4,                // 4*(lane>>5)
                                       const f16x8 B[4], f16* swb, const f16* srb, f16x8 OUT[4])
{
    #pragma unroll
    for (int t = 0; t < 2; ++t){
        f32x16 ac;
        #pragma unroll
        for (int g = 0; g < 4; ++g){
            f32x4 bv = *(const f32x4*)(bs + 32 * t + 8 * g + hf4);
            ac[4*g+0] = bv[0]; ac[4*g+1] = bv[1]; ac[4*g+2] = bv[2]; ac[4*g+3] = bv[3];
        }
        #pragma unroll
        for (int kc = 0; kc < 4; ++kc)
            ac = MFMA32(*(const f16x8*)(wr + t * 2048 + kc * 512), B[kc], ac);
        #pragma unroll
        for (int g = 0; g < 4; ++g)
            *(f16x4*)(swb + 32 * t + 8 * g) = pack4(act<ACTI>(ac[4*g+0]), act<ACTI>(ac[4*g+1]),
                                                    act<ACTI>(ac[4*g+2]), act<ACTI>(ac[4*g+3]));
    }
    #pragma unroll
    for (int kc = 0; kc < 4; ++kc){
        f16x4 lo = *(const f16x4*)(srb + 16 * kc);
        f16x4 hi = *(const f16x4*)(srb + 16 * kc + 4);
        OUT[kc] = cat8(lo, hi);
    }
}

__global__ __launch_bounds__(768, 3) void inr_mfma5_kernel(
    const float* __restrict__ gx, const float* __restrict__ gy,
    const float* __restrict__ gz, const float* __restrict__ gr,
    const float* __restrict__ gnoise,
    const float* __restrict__ W_noise, const float* __restrict__ b_noise,
    const float* __restrict__ W_x, const float* __restrict__ W_y,
    const float* __restrict__ W_z, const float* __restrict__ W_r,
    const float* __restrict__ W1, const float* __restrict__ b1,
    const float* __restrict__ Wg, const float* __restrict__ bg,
    const float* __restrict__ W_out, const float* __restrict__ b_out,
    float* __restrict__ out, int nt, int niter)
{
    // ---- LDS: 161,040 B total (<= 163,840), 1 block (12 waves) per CU -> 3 waves/SIMD ----
    __shared__ __align__(16) f16   wfrag[12][2][4][64][8]; // 96 KB  W^T A-frags [node][mtile][kblk][lane][j]
    __shared__ __align__(16) f16   nfrag[2][64][8];        //  2 KB  W_noise^T A-frags (K=16 exact)
    __shared__ __align__(16) f16   ofrag[4][64][8];        //  4 KB  W_out^T A-frags (rows >=3 zero)
    __shared__ __align__(16) float b_s[12][64];            //  3 KB  node biases (plain)
    __shared__ __align__(16) float wvs[4][64];             //  1 KB  Wx,Wy,Wz,Wr (plain)
    __shared__ __align__(16) float bns[64];                //  256B  b_noise
    __shared__            float bout_s[4];
    __shared__ __align__(16) f16   scratch[12][32][SCR];   // 51 KB  per-wave transpose scratch [wave][pt][feat]

    const int tid  = threadIdx.x;
    const int lane = tid & 63;
    const int wvid = tid >> 6;       // wave id 0..11
    const int n2   = lane & 31;      // point-in-tile (MFMA col)
    const int hf   = lane >> 5;      // half-wave (covers K/row ranges)
    const int hf4  = 4 * hf;

    // ================= PREP: build fragments in LDS (grid=256 -> once per CU) =================
    {   // biases: tid covers 12*64 = 768 exactly
        int node = tid >> 6, f = tid & 63;
        b_s[node][f] = (node == 0) ? b1[f] : bg[(node - 1) * 64 + f];
    }
    if (tid < 256){
        int vec = tid >> 6, f = tid & 63;
        const float* src = (vec == 0) ? W_x : (vec == 1) ? W_y : (vec == 2) ? W_z : W_r;
        wvs[vec][f] = src[f];
    }
    if (tid < 64) bns[tid] = b_noise[tid];
    if (tid < 4)  bout_s[tid] = (tid < 3) ? b_out[tid] : 0.0f;
    if (tid < 128){                                  // nfrag: A[m][k]=W_noise[k][m], k=8*hf+j
        int t = tid >> 6, ln = tid & 63, m = ln & 31, h = ln >> 5;
        f16x8 v;
        #pragma unroll
        for (int j = 0; j < 8; ++j) v[j] = (f16)W_noise[(8 * h + j) * 64 + 32 * t + m];
        *(f16x8*)&nfrag[t][ln][0] = v;
    }
    if (tid < 256){                                  // ofrag: A[m][k]=W_out[k][m] (m<3)
        int kc = tid >> 6, ln = tid & 63, m = ln & 31, h = ln >> 5;
        f16x8 v;
        #pragma unroll
        for (int j = 0; j < 8; ++j){
            int k = 16 * kc + 8 * h + j;
            v[j] = (m < 3) ? (f16)W_out[k * 3 + m] : (f16)0.0f;
        }
        *(f16x8*)&ofrag[kc][ln][0] = v;
    }
    // big weights: coalesced stage into padded scratch (raw fp32), then frag-fill
    {
        float* wraw = (float*)&scratch[0][0][0];     // 64*65*4 = 16.6 KB <= 51 KB
        for (int node = 0; node < 12; ++node){
            const float* Wsrc = (node == 0) ? W1 : (Wg + (node - 1) * 4096);
            __syncthreads();                          // protect wraw (prev iter readers)
            {
                float4 v = ((const float4*)Wsrc)[tid];
                int row = tid >> 4, col = (tid & 15) * 4;
                float* d = wraw + row * WRS + col;
                d[0] = v.x; d[1] = v.y; d[2] = v.z; d[3] = v.w;
            }
            if (tid < 256){
                int i2 = tid + 768;
                float4 v = ((const float4*)Wsrc)[i2];
                int row = i2 >> 4, col = (i2 & 15) * 4;
                float* d = wraw + row * WRS + col;
                d[0] = v.x; d[1] = v.y; d[2] = v.z; d[3] = v.w;
            }
            __syncthreads();
            if (tid < 512){                           // A[m=32t+(ln&31)][k=16kc+8h+j]
                int t = tid >> 8, kc = (tid >> 6) & 3, ln = tid & 63, m = ln & 31, h = ln >> 5;
                f16x8 v;
                #pragma unroll
                for (int j = 0; j < 8; ++j) v[j] = (f16)wraw[(16 * kc + 8 * h + j) * WRS + 32 * t + m];
                *(f16x8*)&wfrag[node][t][kc][ln][0] = v;
            }
        }
        __syncthreads();   // wfrag complete; scratch now free for per-wave use
    }

    // lane-constant scratch pointers (steady-state offsets are immediates; all ops 8B-aligned)
    f16*       swb = &scratch[wvid][n2][hf4];        // write: feat 32t+8g+4hf -> swb + 32t+8g
    const f16* srb = &scratch[wvid][n2][8 * hf];     // read:  feat 16kc+8hf   -> srb + 16kc

    #define WPTR(NI) (&wfrag[NI][0][0][lane][0])
    #define N1(NI, ACTI, A, OUT)  node32<ACTI>(WPTR(NI), &b_s[NI][0], hf4, A, swb, srb, OUT)
    #define N2(NI, ACTI, A, B, OUT) do {                                            \
        f16x8 s_[4];                                                                \
        _Pragma("unroll")                                                           \
        for (int kc_ = 0; kc_ < 4; ++kc_) s_[kc_] = A[kc_] + B[kc_];                \
        node32<ACTI>(WPTR(NI), &b_s[NI][0], hf4, s_, swb, srb, OUT);                \
    } while (0)
    #define N3(NI, ACTI, A, B, C, OUT) do {                                         \
        f16x8 s_[4];                                                                \
        _Pragma("unroll")                                                           \
        for (int kc_ = 0; kc_ < 4; ++kc_) s_[kc_] = A[kc_] + B[kc_] + C[kc_];       \
        node32<ACTI>(WPTR(NI), &b_s[NI][0], hf4, s_, swb, srb, OUT);                \
    } while (0)

    // ================= MAIN LOOP: guarded iters, one 32-pt tile per wave per iter ==========
    for (int it = 0; it < niter; ++it){
        const int tile = (it * gridDim.x + blockIdx.x) * 12 + wvid;
        if (tile >= nt) break;
        const int myp = tile * 32 + n2;

        // ---- input branches ----
        const float xs = gx[myp], ys = gy[myp], zs = gz[myp], rs = gr[myp];
        f16x8 nb;
        {
            const float4 a4 = *(const float4*)(gnoise + (size_t)myp * 16 + 8 * hf);
            const float4 b4 = *(const float4*)(gnoise + (size_t)myp * 16 + 8 * hf + 4);
            nb = cat8(pack4(a4.x, a4.y, a4.z, a4.w), pack4(b4.x, b4.y, b4.z, b4.w));
        }
        // g = sin(elu(z Wz) + gauss(x Wx) + tanh(y Wy) + softplus(r Wr) + tanh(noise Wn + bn))
        f16x8 sg[4];
        {
            #pragma unroll
            for (int t = 0; t < 2; ++t){
                f32x16 ac;
                #pragma unroll
                for (int i = 0; i < 16; ++i) ac[i] = 0.0f;
                ac = MFMA32(*(const f16x8*)&nfrag[t][lane][0], nb, ac);
                #pragma unroll
                for (int g = 0; g < 4; ++g){
                    const int fb = 32 * t + 8 * g + hf4;
                    const f32x4 wx = *(const f32x4*)&wvs[0][fb];
                    const f32x4 wy = *(const f32x4*)&wvs[1][fb];
                    const f32x4 wz = *(const f32x4*)&wvs[2][fb];
                    const f32x4 wr_ = *(const f32x4*)&wvs[3][fb];
                    const f32x4 bn = *(const f32x4*)&bns[fb];
                    float gv[4];
                    #pragma unroll
                    for (int r = 0; r < 4; ++r){
                        float pre = ac[4 * g + r] + bn[r];
                        float v = act_elu(zs * wz[r])
                                + act_gauss(xs * wx[r])
                                + act_tanh(ys * wy[r])
                                + act_softplus(rs * wr_[r])
                                + act_tanh(pre);
                        gv[r] = __sinf(v);
                    }
                    *(f16x4*)(swb + 32 * t + 8 * g) = pack4(gv[0], gv[1], gv[2], gv[3]);
                }
            }
            #pragma unroll
            for (int kc = 0; kc < 4; ++kc){
                f16x4 lo = *(const f16x4*)(srb + 16 * kc);
                f16x4 hi = *(const f16x4*)(srb + 16 * kc + 4);
                sg[kc] = cat8(lo, hi);
            }
        }

        f16x8 h0[4], r0[4], r1[4], r2[4], r3[4];
        N1(0,  0, sg, h0);                 // h0 = tanh(g @ W1 + b1)
        N1(1,  0, h0, r0);                 // h1 = tanh(h0 W)
        N1(2,  1, r0, r1);                 // h2 = elu(h1 W)
        N2(3,  2, r1, h0, r2);             // h3 = softplus((h2+h0) W)
        N3(4,  3, r2, r0, h0, r3);         // h4 = sin((h3+h1+h0) W)
        N2(5,  4, r3, r1, r0);             // h5 = gauss((h4+h2) W)
        N2(6,  5, r0, r2, r1);             // h6 = sigmoid((h5+h3) W)
        N2(7,  0, r1, r3, r2);             // h7 = tanh((h6+h4) W)
        N3(8,  1, r2, r0, h0, r3);         // h8 = elu((h7+h5+h0) W)
        N2(9,  2, r3, r1, r0);             // h9 = softplus((h8+h6) W)
        N2(10, 3, r0, r2, r1);             // h10= sin((h9+h7) W)
        N2(11, 4, r1, r3, r2);             // h11= gauss((h10+h8) W)

        // ---- output: sigmoid(h11 @ W_out + b_out), h11 in r2; m-tile 0, rows 0..2, hf=0 ----
        {
            f32x16 om;
            #pragma unroll
            for (int i = 0; i < 16; ++i) om[i] = 0.0f;
            #pragma unroll
            for (int kc = 0; kc < 4; ++kc)
                om = MFMA32(*(const f16x8*)&ofrag[kc][lane][0], r2[kc], om);
            if (hf == 0){
                #pragma unroll
                for (int r = 0; r < 3; ++r)
                    out[(size_t)myp * 3 + r] = act_sigmoid(om[r] + bout_s[r]);
            }
        }
    }
    #undef N1
    #undef N2
    #undef N3
    #undef WPTR
}

extern "C" void kernel_launch(void* const* d_in, const int* in_sizes, int n_in,
                              void* d_out, int out_size, void* d_ws, size_t ws_size,
                              hipStream_t stream)
{
    const float* x       = (const float*)d_in[0];
    const float* y       = (const float*)d_in[1];
    const float* z       = (const float*)d_in[2];
    const float* r       = (const float*)d_in[3];
    const float* noise   = (const float*)d_in[4];
    const float* W_noise = (const float*)d_in[5];
    const float* b_noise = (const float*)d_in[6];
    const float* W_x     = (const float*)d_in[7];
    const float* W_y     = (const float*)d_in[8];
    const float* W_z     = (const float*)d_in[9];
    const float* W_r     = (const float*)d_in[10];
    const float* W1      = (const float*)d_in[11];
    const float* b1      = (const float*)d_in[12];
    const float* Wg      = (const float*)d_in[13];
    const float* bg      = (const float*)d_in[14];
    const float* W_out   = (const float*)d_in[15];
    const float* b_out   = (const float*)d_in[16];
    float* out = (float*)d_out;

    const int n     = in_sizes[0];
    const int nt    = n / 32;                       // 32-pt tiles
    const int grid  = 256;                          // 1 block per CU; prep once per CU
    const int tiles_per_pass = grid * 12;
    const int niter = (nt + tiles_per_pass - 1) / tiles_per_pass;
    inr_mfma5_kernel<<<dim3(grid), dim3(768), 0, stream>>>(
        x, y, z, r, noise, W_noise, b_noise, W_x, W_y, W_z, W_r,
        W1, b1, Wg, bg, W_out, b_out, out, nt, niter);
}

// Round 8
// 200.408 us; speedup vs baseline: 1.0052x; 1.0052x over previous
//
#include <hip/hip_runtime.h>

#define WRS 65     // staged fp32 weight row stride: breaks bank conflicts in frag-fill

typedef _Float16 f16;
typedef f16  f16x4 __attribute__((ext_vector_type(4)));
typedef f16  f16x8 __attribute__((ext_vector_type(8)));
typedef __fp16 h16x2 __attribute__((ext_vector_type(2)));  // cvt_pkrtz native return type
typedef float f32x4  __attribute__((ext_vector_type(4)));
typedef float f32x16 __attribute__((ext_vector_type(16)));
typedef unsigned int u32;
typedef u32 u32x2 __attribute__((ext_vector_type(2)));
typedef u32 u32x4 __attribute__((ext_vector_type(4)));

__device__ __forceinline__ float frcp(float x){
#if __has_builtin(__builtin_amdgcn_rcpf)
    return __builtin_amdgcn_rcpf(x);
#else
    return 1.0f / x;
#endif
}

// ---------- activations (fp32, identical numerics to R4-R7) ----------
__device__ __forceinline__ float act_tanh(float x){
    return 1.0f - 2.0f * frcp(1.0f + __expf(2.0f * x));
}
__device__ __forceinline__ float act_elu(float x){
    float e = __expf(x) - 1.0f;
    return x > 0.0f ? x : e;
}
__device__ __forceinline__ float act_softplus(float x){
    float a = fabsf(x);
    return fmaxf(x, 0.0f) + __logf(1.0f + __expf(-a));
}
__device__ __forceinline__ float act_gauss(float x){
    return __expf(-0.5f * x * x);
}
__device__ __forceinline__ float act_sigmoid(float x){
    return frcp(1.0f + __expf(-x));
}
template<int A> __device__ __forceinline__ float act(float v){
    if constexpr (A == 0) return act_tanh(v);
    else if constexpr (A == 1) return act_elu(v);
    else if constexpr (A == 2) return act_softplus(v);
    else if constexpr (A == 3) return __sinf(v);
    else if constexpr (A == 4) return act_gauss(v);
    else                       return act_sigmoid(v);
}

// dword-built packing (no per-element vector inserts)
__device__ __forceinline__ f16x4 pack4(float a, float b, float c, float d){
    u32x2 u;
    u[0] = __builtin_bit_cast(u32, __builtin_amdgcn_cvt_pkrtz(a, b));
    u[1] = __builtin_bit_cast(u32, __builtin_amdgcn_cvt_pkrtz(c, d));
    return __builtin_bit_cast(f16x4, u);
}
__device__ __forceinline__ f16x8 cat8(f16x4 lo, f16x4 hi){
    u32x2 a = __builtin_bit_cast(u32x2, lo), b = __builtin_bit_cast(u32x2, hi);
    u32x4 u; u[0] = a[0]; u[1] = a[1]; u[2] = b[0]; u[3] = b[1];
    return __builtin_bit_cast(f16x8, u);
}

#define MFMA32(a, b, c) __builtin_amdgcn_mfma_f32_32x32x16_f16((a), (b), (c), 0, 0, 0)

// K-permutation: k-slot (kc, 8h+j) holds feature 8*kc + 32*(j>>2) + 4*h + (j&3).
// With this pi, next node's B-frag[kc] = cat(pk[t=0][g=kc], pk[t=1][g=kc]) -- registers only.

// one node, one 32-pt tile: acc=bias; acc += W^T @ B (8 MFMAs); act; repack to B-frags in regs
template<int ACTI>
__device__ __forceinline__ void node32(const f16* __restrict__ wr,   // &wfrag[ni][0][0][lane][0]
                                       const float* __restrict__ bs, // &b_s[ni][0]
                                       const int hf4,                // 4*(lane>>5)
                                       const f16x8 B[4], f16x8 OUT[4])
{
    f16x4 pk[2][4];
    #pragma unroll
    for (int t = 0; t < 2; ++t){
        f32x16 ac;
        #pragma unroll
        for (int g = 0; g < 4; ++g){
            f32x4 bv = *(const f32x4*)(bs + 32 * t + 8 * g + hf4);
            ac[4*g+0] = bv[0]; ac[4*g+1] = bv[1]; ac[4*g+2] = bv[2]; ac[4*g+3] = bv[3];
        }
        #pragma unroll
        for (int kc = 0; kc < 4; ++kc)
            ac = MFMA32(*(const f16x8*)(wr + t * 2048 + kc * 512), B[kc], ac);
        #pragma unroll
        for (int g = 0; g < 4; ++g)
            pk[t][g] = pack4(act<ACTI>(ac[4*g+0]), act<ACTI>(ac[4*g+1]),
                             act<ACTI>(ac[4*g+2]), act<ACTI>(ac[4*g+3]));
    }
    #pragma unroll
    for (int kc = 0; kc < 4; ++kc) OUT[kc] = cat8(pk[0][kc], pk[1][kc]);
}

__global__ __launch_bounds__(768, 3) void inr_mfma6_kernel(
    const float* __restrict__ gx, const float* __restrict__ gy,
    const float* __restrict__ gz, const float* __restrict__ gr,
    const float* __restrict__ gnoise,
    const float* __restrict__ W_noise, const float* __restrict__ b_noise,
    const float* __restrict__ W_x, const float* __restrict__ W_y,
    const float* __restrict__ W_z, const float* __restrict__ W_r,
    const float* __restrict__ W1, const float* __restrict__ b1,
    const float* __restrict__ Wg, const float* __restrict__ bg,
    const float* __restrict__ W_out, const float* __restrict__ b_out,
    float* __restrict__ out, int nt, int niter)
{
    // ---- LDS: ~123 KB total, 1 block (12 waves) per CU -> 3 waves/SIMD ----
    __shared__ __align__(16) f16   wfrag[12][2][4][64][8]; // 96 KB  W^T A-frags [node][mtile][kblk][lane][j], pi-permuted k
    __shared__ __align__(16) f16   nfrag[2][64][8];        //  2 KB  W_noise^T A-frags (K=16, no pi)
    __shared__ __align__(16) f16   ofrag[4][64][8];        //  4 KB  W_out^T A-frags (pi-permuted, rows >=3 zero)
    __shared__ __align__(16) float b_s[12][64];            //  3 KB  node biases
    __shared__ __align__(16) float wvs[4][64];             //  1 KB  Wx,Wy,Wz,Wr
    __shared__ __align__(16) float bns[64];                //  256B  b_noise
    __shared__            float bout_s[4];
    __shared__ __align__(16) float wstage[64 * WRS];       // 16.6 KB weight staging

    const int tid  = threadIdx.x;
    const int lane = tid & 63;
    const int n2   = lane & 31;      // point-in-tile (MFMA col)
    const int hf   = lane >> 5;      // half-wave
    const int hf4  = 4 * hf;

    // ================= PREP: build fragments in LDS (grid=256 -> once per CU) =================
    {   // biases: tid covers 12*64 = 768 exactly
        int node = tid >> 6, f = tid & 63;
        b_s[node][f] = (node == 0) ? b1[f] : bg[(node - 1) * 64 + f];
    }
    if (tid < 256){
        int vec = tid >> 6, f = tid & 63;
        const float* src = (vec == 0) ? W_x : (vec == 1) ? W_y : (vec == 2) ? W_z : W_r;
        wvs[vec][f] = src[f];
    }
    if (tid < 64) bns[tid] = b_noise[tid];
    if (tid < 4)  bout_s[tid] = (tid < 3) ? b_out[tid] : 0.0f;
    if (tid < 128){                                  // nfrag: A[m][k]=W_noise[k][m], k=8h+j (no pi)
        int t = tid >> 6, ln = tid & 63, m = ln & 31, h = ln >> 5;
        f16x8 v;
        #pragma unroll
        for (int j = 0; j < 8; ++j) v[j] = (f16)W_noise[(8 * h + j) * 64 + 32 * t + m];
        *(f16x8*)&nfrag[t][ln][0] = v;
    }
    if (tid < 256){                                  // ofrag with pi: A[m][k]=W_out[pi(kc,8h+j)][m] (m<3)
        int kc = tid >> 6, ln = tid & 63, m = ln & 31, h = ln >> 5;
        f16x8 v;
        #pragma unroll
        for (int j = 0; j < 8; ++j){
            int kf = 8 * kc + 32 * (j >> 2) + 4 * h + (j & 3);
            v[j] = (m < 3) ? (f16)W_out[kf * 3 + m] : (f16)0.0f;
        }
        *(f16x8*)&ofrag[kc][ln][0] = v;
    }
    // big weights: coalesced stage into padded buffer (raw fp32), then pi-permuted frag-fill
    for (int node = 0; node < 12; ++node){
        const float* Wsrc = (node == 0) ? W1 : (Wg + (node - 1) * 4096);
        __syncthreads();                          // protect wstage (prev iter readers)
        {
            float4 v = ((const float4*)Wsrc)[tid];
            int row = tid >> 4, col = (tid & 15) * 4;
            float* d = wstage + row * WRS + col;
            d[0] = v.x; d[1] = v.y; d[2] = v.z; d[3] = v.w;
        }
        if (tid < 256){
            int i2 = tid + 768;
            float4 v = ((const float4*)Wsrc)[i2];
            int row = i2 >> 4, col = (i2 & 15) * 4;
            float* d = wstage + row * WRS + col;
            d[0] = v.x; d[1] = v.y; d[2] = v.z; d[3] = v.w;
        }
        __syncthreads();
        if (tid < 512){                           // A[m=32t+(ln&31)][pi(kc, 8h+j)]
            int t = tid >> 8, kc = (tid >> 6) & 3, ln = tid & 63, m = ln & 31, h = ln >> 5;
            f16x8 v;
            #pragma unroll
            for (int j = 0; j < 8; ++j){
                int kf = 8 * kc + 32 * (j >> 2) + 4 * h + (j & 3);
                v[j] = (f16)wstage[kf * WRS + 32 * t + m];
            }
            *(f16x8*)&wfrag[node][t][kc][ln][0] = v;
        }
    }
    __syncthreads();   // wfrag complete

    #define WPTR(NI) (&wfrag[NI][0][0][lane][0])
    #define N1(NI, ACTI, A, OUT)  node32<ACTI>(WPTR(NI), &b_s[NI][0], hf4, A, OUT)
    #define N2(NI, ACTI, A, B, OUT) do {                                            \
        f16x8 s_[4];                                                                \
        _Pragma("unroll")                                                           \
        for (int kc_ = 0; kc_ < 4; ++kc_) s_[kc_] = A[kc_] + B[kc_];                \
        node32<ACTI>(WPTR(NI), &b_s[NI][0], hf4, s_, OUT);                          \
    } while (0)
    #define N3(NI, ACTI, A, B, C, OUT) do {                                         \
        f16x8 s_[4];                                                                \
        _Pragma("unroll")                                                           \
        for (int kc_ = 0; kc_ < 4; ++kc_) s_[kc_] = A[kc_] + B[kc_] + C[kc_];       \
        node32<ACTI>(WPTR(NI), &b_s[NI][0], hf4, s_, OUT);                          \
    } while (0)

    const int wvid = tid >> 6;       // wave id 0..11

    // ================= MAIN LOOP: guarded iters, one 32-pt tile per wave per iter ==========
    for (int it = 0; it < niter; ++it){
        const int tile = (it * gridDim.x + blockIdx.x) * 12 + wvid;
        if (tile >= nt) break;
        const int myp = tile * 32 + n2;

        // ---- input branches ----
        const float xs = gx[myp], ys = gy[myp], zs = gz[myp], rs = gr[myp];
        f16x8 nb;
        {
            const float4 a4 = *(const float4*)(gnoise + (size_t)myp * 16 + 8 * hf);
            const float4 b4 = *(const float4*)(gnoise + (size_t)myp * 16 + 8 * hf + 4);
            nb = cat8(pack4(a4.x, a4.y, a4.z, a4.w), pack4(b4.x, b4.y, b4.z, b4.w));
        }
        // g = sin(elu(z Wz) + gauss(x Wx) + tanh(y Wy) + softplus(r Wr) + tanh(noise Wn + bn))
        f16x8 sg[4];
        {
            f16x4 pkg[2][4];
            #pragma unroll
            for (int t = 0; t < 2; ++t){
                f32x16 ac;
                #pragma unroll
                for (int i = 0; i < 16; ++i) ac[i] = 0.0f;
                ac = MFMA32(*(const f16x8*)&nfrag[t][lane][0], nb, ac);
                #pragma unroll
                for (int g = 0; g < 4; ++g){
                    const int fb = 32 * t + 8 * g + hf4;
                    const f32x4 wx = *(const f32x4*)&wvs[0][fb];
                    const f32x4 wy = *(const f32x4*)&wvs[1][fb];
                    const f32x4 wz = *(const f32x4*)&wvs[2][fb];
                    const f32x4 wr_ = *(const f32x4*)&wvs[3][fb];
                    const f32x4 bn = *(const f32x4*)&bns[fb];
                    float gv[4];
                    #pragma unroll
                    for (int r = 0; r < 4; ++r){
                        float pre = ac[4 * g + r] + bn[r];
                        float v = act_elu(zs * wz[r])
                                + act_gauss(xs * wx[r])
                                + act_tanh(ys * wy[r])
                                + act_softplus(rs * wr_[r])
                                + act_tanh(pre);
                        gv[r] = __sinf(v);
                    }
                    pkg[t][g] = pack4(gv[0], gv[1], gv[2], gv[3]);
                }
            }
            #pragma unroll
            for (int kc = 0; kc < 4; ++kc) sg[kc] = cat8(pkg[0][kc], pkg[1][kc]);
        }

        f16x8 h0[4], r0[4], r1[4], r2[4], r3[4];
        N1(0,  0, sg, h0);                 // h0 = tanh(g @ W1 + b1)
        N1(1,  0, h0, r0);                 // h1 = tanh(h0 W)
        N1(2,  1, r0, r1);                 // h2 = elu(h1 W)
        N2(3,  2, r1, h0, r2);             // h3 = softplus((h2+h0) W)
        N3(4,  3, r2, r0, h0, r3);         // h4 = sin((h3+h1+h0) W)
        N2(5,  4, r3, r1, r0);             // h5 = gauss((h4+h2) W)
        N2(6,  5, r0, r2, r1);             // h6 = sigmoid((h5+h3) W)
        N2(7,  0, r1, r3, r2);             // h7 = tanh((h6+h4) W)
        N3(8,  1, r2, r0, h0, r3);         // h8 = elu((h7+h5+h0) W)
        N2(9,  2, r3, r1, r0);             // h9 = softplus((h8+h6) W)
        N2(10, 3, r0, r2, r1);             // h10= sin((h9+h7) W)
        N2(11, 4, r1, r3, r2);             // h11= gauss((h10+h8) W)

        // ---- output: sigmoid(h11 @ W_out + b_out), h11 in r2; rows 0..2 live in hf=0, regs 0..2 ----
        {
            f32x16 om;
            #pragma unroll
            for (int i = 0; i < 16; ++i) om[i] = 0.0f;
            #pragma unroll
            for (int kc = 0; kc < 4; ++kc)
                om = MFMA32(*(const f16x8*)&ofrag[kc][lane][0], r2[kc], om);
            if (hf == 0){
                #pragma unroll
                for (int r = 0; r < 3; ++r)
                    out[(size_t)myp * 3 + r] = act_sigmoid(om[r] + bout_s[r]);
            }
        }
    }
    #undef N1
    #undef N2
    #undef N3
    #undef WPTR
}

extern "C" void kernel_launch(void* const* d_in, const int* in_sizes, int n_in,
                              void* d_out, int out_size, void* d_ws, size_t ws_size,
                              hipStream_t stream)
{
    const float* x       = (const float*)d_in[0];
    const float* y       = (const float*)d_in[1];
    const float* z       = (const float*)d_in[2];
    const float* r       = (const float*)d_in[3];
    const float* noise   = (const float*)d_in[4];
    const float* W_noise = (const float*)d_in[5];
    const float* b_noise = (const float*)d_in[6];
    const float* W_x     = (const float*)d_in[7];
    const float* W_y     = (const float*)d_in[8];
    const float* W_z     = (const float*)d_in[9];
    const float* W_r     = (const float*)d_in[10];
    const float* W1      = (const float*)d_in[11];
    const float* b1      = (const float*)d_in[12];
    const float* Wg      = (const float*)d_in[13];
    const float* bg      = (const float*)d_in[14];
    const float* W_out   = (const float*)d_in[15];
    const float* b_out   = (const float*)d_in[16];
    float* out = (float*)d_out;

    const int n     = in_sizes[0];
    const int nt    = n / 32;                       // 32-pt tiles
    const int grid  = 256;                          // 1 block per CU; prep once per CU
    const int tiles_per_pass = grid * 12;
    const int niter = (nt + tiles_per_pass - 1) / tiles_per_pass;
    inr_mfma6_kernel<<<dim3(grid), dim3(768), 0, stream>>>(
        x, y, z, r, noise, W_noise, b_noise, W_x, W_y, W_z, W_r,
        W1, b1, Wg, bg, W_out, b_out, out, nt, niter);
}

// Round 9
// 166.908 us; speedup vs baseline: 1.2069x; 1.2007x over previous
//
#include <hip/hip_runtime.h>

#define WRS 65     // staged fp32 weight row stride: breaks bank conflicts in frag-fill

typedef _Float16 f16;
typedef f16  f16x4 __attribute__((ext_vector_type(4)));
typedef f16  f16x8 __attribute__((ext_vector_type(8)));
typedef __fp16 h16x2 __attribute__((ext_vector_type(2)));  // cvt_pkrtz native return type
typedef float f32x4  __attribute__((ext_vector_type(4)));
typedef float f32x16 __attribute__((ext_vector_type(16)));
typedef unsigned int u32;
typedef u32 u32x2 __attribute__((ext_vector_type(2)));
typedef u32 u32x4 __attribute__((ext_vector_type(4)));

#define LOG2E   1.4426950408889634f
#define LN2     0.6931471805599453f
#define C_TANH  2.8853900817779268f    // 2*log2(e)
#define C_SIN   0.15915494309189535f   // 1/(2*pi)
#define C_SIG  -1.4426950408889634f    // -log2(e)
#define C_GAU  -0.7213475204444817f    // -log2(e)/2

// per-node arg prescale baked into W,b at prep: acts 0=tanh,1=elu,2=softplus,3=sin,4=gauss,5=sigmoid
__device__ __constant__ float NSCL[12] = {
    C_TANH, C_TANH, 1.0f, 1.0f, C_SIN, 1.0f, C_SIG, C_TANH, 1.0f, 1.0f, C_SIN, 1.0f
};

__device__ __forceinline__ float frcp(float x){ return __builtin_amdgcn_rcpf(x); }
__device__ __forceinline__ float fexp2(float x){ return __builtin_amdgcn_exp2f(x); }
__device__ __forceinline__ float flog2(float x){ return __builtin_amdgcn_logf(x); }
__device__ __forceinline__ float fsin1(float x){ return __builtin_amdgcn_sinf(x); } // arg in revolutions

// ---------- activations on PRESCALED args (see NSCL) ----------
template<int A> __device__ __forceinline__ float act(float v){
    if constexpr (A == 0){                       // tanh; v = 2log2e*x
        float t = fexp2(v);
        return 1.0f - 2.0f * frcp(1.0f + t);
    } else if constexpr (A == 1){                // elu; v raw
        float e = fexp2(v * LOG2E) - 1.0f;
        return v > 0.0f ? v : e;
    } else if constexpr (A == 2){                // softplus; v raw
        float p = fexp2(-LOG2E * fabsf(v));
        return fmaxf(v, 0.0f) + LN2 * flog2(1.0f + p);
    } else if constexpr (A == 3){                // sin; v = x/(2pi), |v| small -> no fract needed
        return fsin1(v);
    } else if constexpr (A == 4){                // gauss; v raw
        return fexp2(v * v * C_GAU);
    } else {                                     // sigmoid; v = -log2e*x
        return frcp(1.0f + fexp2(v));
    }
}

// dword-built packing
__device__ __forceinline__ f16x4 pack4(float a, float b, float c, float d){
    u32x2 u;
    u[0] = __builtin_bit_cast(u32, __builtin_amdgcn_cvt_pkrtz(a, b));
    u[1] = __builtin_bit_cast(u32, __builtin_amdgcn_cvt_pkrtz(c, d));
    return __builtin_bit_cast(f16x4, u);
}
__device__ __forceinline__ f16x8 cat8(f16x4 lo, f16x4 hi){
    u32x2 a = __builtin_bit_cast(u32x2, lo), b = __builtin_bit_cast(u32x2, hi);
    u32x4 u; u[0] = a[0]; u[1] = a[1]; u[2] = b[0]; u[3] = b[1];
    return __builtin_bit_cast(f16x8, u);
}

#define MFMA32(a, b, c) __builtin_amdgcn_mfma_f32_32x32x16_f16((a), (b), (c), 0, 0, 0)

// K-permutation pi: k-slot (kc, 8h+j) holds feature 8*kc + 32*(j>>2) + 4*h + (j&3);
// next node's B-frag[kc] = cat(pk[t=0][g=kc], pk[t=1][g=kc]) -- registers only.
template<int ACTI>
__device__ __forceinline__ void node32(const f16* __restrict__ wr,   // &wfrag[ni][0][0][lane][0]
                                       const float* __restrict__ bs, // &b_s[ni][0] (prescaled)
                                       const int hf4,                // 4*(lane>>5)
                                       const f16x8 B[4], f16x8 OUT[4])
{
    f16x4 pk[2][4];
    #pragma unroll
    for (int t = 0; t < 2; ++t){
        f32x16 ac;
        #pragma unroll
        for (int g = 0; g < 4; ++g){
            f32x4 bv = *(const f32x4*)(bs + 32 * t + 8 * g + hf4);
            ac[4*g+0] = bv[0]; ac[4*g+1] = bv[1]; ac[4*g+2] = bv[2]; ac[4*g+3] = bv[3];
        }
        #pragma unroll
        for (int kc = 0; kc < 4; ++kc)
            ac = MFMA32(*(const f16x8*)(wr + t * 2048 + kc * 512), B[kc], ac);
        #pragma unroll
        for (int g = 0; g < 4; ++g)
            pk[t][g] = pack4(act<ACTI>(ac[4*g+0]), act<ACTI>(ac[4*g+1]),
                             act<ACTI>(ac[4*g+2]), act<ACTI>(ac[4*g+3]));
    }
    #pragma unroll
    for (int kc = 0; kc < 4; ++kc) OUT[kc] = cat8(pk[0][kc], pk[1][kc]);
}

__global__ __launch_bounds__(1024, 1) void inr_mfma7_kernel(
    const float* __restrict__ gx, const float* __restrict__ gy,
    const float* __restrict__ gz, const float* __restrict__ gr,
    const float* __restrict__ gnoise,
    const float* __restrict__ W_noise, const float* __restrict__ b_noise,
    const float* __restrict__ W_x, const float* __restrict__ W_y,
    const float* __restrict__ W_z, const float* __restrict__ W_r,
    const float* __restrict__ W1, const float* __restrict__ b1,
    const float* __restrict__ Wg, const float* __restrict__ bg,
    const float* __restrict__ W_out, const float* __restrict__ b_out,
    float* __restrict__ out, int nt, int niter)
{
    // ---- LDS ~123 KB, 1 block (16 waves) per CU -> 4 waves/SIMD ----
    __shared__ __align__(16) f16   wfrag[12][2][4][64][8]; // 96 KB  prescaled W^T A-frags, pi-permuted k
    __shared__ __align__(16) f16   nfrag[2][64][8];        //  2 KB  2log2e*W_noise^T
    __shared__ __align__(16) f16   ofrag[4][64][8];        //  4 KB  -log2e*W_out^T (pi, rows>=3 zero)
    __shared__ __align__(16) float b_s[12][64];            //  3 KB  prescaled biases
    __shared__ __align__(16) float wvs[4][64];             //  1 KB  [0]=C_GAU*Wx^2, [1]=2log2e*Wy, [2]=Wz, [3]=Wr
    __shared__ __align__(16) float bns[64];                //  256B  2log2e*b_noise
    __shared__            float bout_s[4];
    __shared__ __align__(16) float wstage[64 * WRS];       // 16.6 KB weight staging

    const int tid  = threadIdx.x;
    const int lane = tid & 63;
    const int n2   = lane & 31;      // point-in-tile (MFMA col)
    const int hf   = lane >> 5;      // half-wave
    const int hf4  = 4 * hf;

    // ================= PREP (grid=256 -> once per CU) =================
    if (tid < 768){
        int node = tid >> 6, f = tid & 63;
        b_s[node][f] = NSCL[node] * ((node == 0) ? b1[f] : bg[(node - 1) * 64 + f]);
    }
    if (tid < 256){
        int vec = tid >> 6, f = tid & 63;
        float v;
        if      (vec == 0){ float w = W_x[f]; v = C_GAU * w * w; }
        else if (vec == 1){ v = C_TANH * W_y[f]; }
        else if (vec == 2){ v = W_z[f]; }
        else              { v = W_r[f]; }
        wvs[vec][f] = v;
    }
    if (tid < 64) bns[tid] = C_TANH * b_noise[tid];
    if (tid < 4)  bout_s[tid] = (tid < 3) ? C_SIG * b_out[tid] : 0.0f;
    if (tid < 128){                                  // nfrag: A[m][k]=2log2e*W_noise[k][m], k=8h+j
        int t = tid >> 6, ln = tid & 63, m = ln & 31, h = ln >> 5;
        f16x8 v;
        #pragma unroll
        for (int j = 0; j < 8; ++j) v[j] = (f16)(C_TANH * W_noise[(8 * h + j) * 64 + 32 * t + m]);
        *(f16x8*)&nfrag[t][ln][0] = v;
    }
    if (tid < 256){                                  // ofrag: A[m][k]=-log2e*W_out[pi][m] (m<3)
        int kc = tid >> 6, ln = tid & 63, m = ln & 31, h = ln >> 5;
        f16x8 v;
        #pragma unroll
        for (int j = 0; j < 8; ++j){
            int kf = 8 * kc + 32 * (j >> 2) + 4 * h + (j & 3);
            v[j] = (m < 3) ? (f16)(C_SIG * W_out[kf * 3 + m]) : (f16)0.0f;
        }
        *(f16x8*)&ofrag[kc][ln][0] = v;
    }
    // big weights: coalesced stage (1 float4/thread = full 64x64), then prescaled pi frag-fill
    for (int node = 0; node < 12; ++node){
        const float* Wsrc = (node == 0) ? W1 : (Wg + (node - 1) * 4096);
        const float  scl  = NSCL[node];
        __syncthreads();                          // protect wstage (prev iter readers)
        {
            float4 v = ((const float4*)Wsrc)[tid];
            int row = tid >> 4, col = (tid & 15) * 4;
            float* d = wstage + row * WRS + col;
            d[0] = v.x; d[1] = v.y; d[2] = v.z; d[3] = v.w;
        }
        __syncthreads();
        if (tid < 512){                           // A[m=32t+(ln&31)][pi(kc, 8h+j)]
            int t = tid >> 8, kc = (tid >> 6) & 3, ln = tid & 63, m = ln & 31, h = ln >> 5;
            f16x8 v;
            #pragma unroll
            for (int j = 0; j < 8; ++j){
                int kf = 8 * kc + 32 * (j >> 2) + 4 * h + (j & 3);
                v[j] = (f16)(scl * wstage[kf * WRS + 32 * t + m]);
            }
            *(f16x8*)&wfrag[node][t][kc][ln][0] = v;
        }
    }
    __syncthreads();   // wfrag complete

    #define WPTR(NI) (&wfrag[NI][0][0][lane][0])
    #define N1(NI, ACTI, A, OUT)  node32<ACTI>(WPTR(NI), &b_s[NI][0], hf4, A, OUT)
    #define N2(NI, ACTI, A, B, OUT) do {                                            \
        f16x8 s_[4];                                                                \
        _Pragma("unroll")                                                           \
        for (int kc_ = 0; kc_ < 4; ++kc_) s_[kc_] = A[kc_] + B[kc_];                \
        node32<ACTI>(WPTR(NI), &b_s[NI][0], hf4, s_, OUT);                          \
    } while (0)
    #define N3(NI, ACTI, A, B, C, OUT) do {                                         \
        f16x8 s_[4];                                                                \
        _Pragma("unroll")                                                           \
        for (int kc_ = 0; kc_ < 4; ++kc_) s_[kc_] = A[kc_] + B[kc_] + C[kc_];       \
        node32<ACTI>(WPTR(NI), &b_s[NI][0], hf4, s_, OUT);                          \
    } while (0)

    const int wvid = tid >> 6;       // wave id 0..15

    // ================= MAIN LOOP: one 32-pt tile per wave per iter =================
    for (int it = 0; it < niter; ++it){
        const int tile = (it * gridDim.x + blockIdx.x) * 16 + wvid;
        if (tile >= nt) break;
        const int myp = tile * 32 + n2;

        // ---- input branches ----
        const float xs = gx[myp], ys = gy[myp], zs = gz[myp], rs = gr[myp];
        const float xs2 = xs * xs;                 // pairs with wvs[0] = C_GAU*Wx^2
        f16x8 nb;
        {
            const float4 a4 = *(const float4*)(gnoise + (size_t)myp * 16 + 8 * hf);
            const float4 b4 = *(const float4*)(gnoise + (size_t)myp * 16 + 8 * hf + 4);
            nb = cat8(pack4(a4.x, a4.y, a4.z, a4.w), pack4(b4.x, b4.y, b4.z, b4.w));
        }
        // g = sin(elu(z Wz) + gauss(x Wx) + tanh(y Wy) + softplus(r Wr) + tanh(noise Wn + bn))
        f16x8 sg[4];
        {
            f16x4 pkg[2][4];
            #pragma unroll
            for (int t = 0; t < 2; ++t){
                f32x16 ac;
                #pragma unroll
                for (int i = 0; i < 16; ++i) ac[i] = 0.0f;
                ac = MFMA32(*(const f16x8*)&nfrag[t][lane][0], nb, ac);
                #pragma unroll
                for (int g = 0; g < 4; ++g){
                    const int fb = 32 * t + 8 * g + hf4;
                    const f32x4 wx2 = *(const f32x4*)&wvs[0][fb];   // C_GAU*Wx^2
                    const f32x4 wyt = *(const f32x4*)&wvs[1][fb];   // 2log2e*Wy
                    const f32x4 wz  = *(const f32x4*)&wvs[2][fb];
                    const f32x4 wr_ = *(const f32x4*)&wvs[3][fb];
                    const f32x4 bn  = *(const f32x4*)&bns[fb];      // 2log2e*b_noise
                    float gv[4];
                    #pragma unroll
                    for (int r = 0; r < 4; ++r){
                        // elu(zs*wz)
                        float az = zs * wz[r];
                        float ez = fexp2(az * LOG2E) - 1.0f;
                        float velu = az > 0.0f ? az : ez;
                        // gauss(xs*wx) = exp2(xs^2 * C_GAU*wx^2)
                        float vga = fexp2(xs2 * wx2[r]);
                        // tanh(ys*wy), prescaled
                        float ty = fexp2(ys * wyt[r]);
                        float vty = 1.0f - 2.0f * frcp(1.0f + ty);
                        // softplus(rs*wr)
                        float ar = rs * wr_[r];
                        float vsp = fmaxf(ar, 0.0f) + LN2 * flog2(1.0f + fexp2(-LOG2E * fabsf(ar)));
                        // tanh(noise@Wn + bn), prescaled
                        float tp = fexp2(ac[4 * g + r] + bn[r]);
                        float vtp = 1.0f - 2.0f * frcp(1.0f + tp);
                        float v = velu + vga + vty + vsp + vtp;
                        gv[r] = fsin1(v * C_SIN);
                    }
                    pkg[t][g] = pack4(gv[0], gv[1], gv[2], gv[3]);
                }
            }
            #pragma unroll
            for (int kc = 0; kc < 4; ++kc) sg[kc] = cat8(pkg[0][kc], pkg[1][kc]);
        }

        f16x8 h0[4], r0[4], r1[4], r2[4], r3[4];
        N1(0,  0, sg, h0);                 // h0 = tanh(g @ W1 + b1)
        N1(1,  0, h0, r0);                 // h1 = tanh(h0 W)
        N1(2,  1, r0, r1);                 // h2 = elu(h1 W)
        N2(3,  2, r1, h0, r2);             // h3 = softplus((h2+h0) W)
        N3(4,  3, r2, r0, h0, r3);         // h4 = sin((h3+h1+h0) W)
        N2(5,  4, r3, r1, r0);             // h5 = gauss((h4+h2) W)
        N2(6,  5, r0, r2, r1);             // h6 = sigmoid((h5+h3) W)
        N2(7,  0, r1, r3, r2);             // h7 = tanh((h6+h4) W)
        N3(8,  1, r2, r0, h0, r3);         // h8 = elu((h7+h5+h0) W)
        N2(9,  2, r3, r1, r0);             // h9 = softplus((h8+h6) W)
        N2(10, 3, r0, r2, r1);             // h10= sin((h9+h7) W)
        N2(11, 4, r1, r3, r2);             // h11= gauss((h10+h8) W)

        // ---- output: sigmoid folded into ofrag: out = rcp(1+exp2(om+bout)) ----
        {
            f32x16 om;
            #pragma unroll
            for (int i = 0; i < 16; ++i) om[i] = 0.0f;
            #pragma unroll
            for (int kc = 0; kc < 4; ++kc)
                om = MFMA32(*(const f16x8*)&ofrag[kc][lane][0], r2[kc], om);
            if (hf == 0){
                #pragma unroll
                for (int r = 0; r < 3; ++r)
                    out[(size_t)myp * 3 + r] = frcp(1.0f + fexp2(om[r] + bout_s[r]));
            }
        }
    }
    #undef N1
    #undef N2
    #undef N3
    #undef WPTR
}

extern "C" void kernel_launch(void* const* d_in, const int* in_sizes, int n_in,
                              void* d_out, int out_size, void* d_ws, size_t ws_size,
                              hipStream_t stream)
{
    const float* x       = (const float*)d_in[0];
    const float* y       = (const float*)d_in[1];
    const float* z       = (const float*)d_in[2];
    const float* r       = (const float*)d_in[3];
    const float* noise   = (const float*)d_in[4];
    const float* W_noise = (const float*)d_in[5];
    const float* b_noise = (const float*)d_in[6];
    const float* W_x     = (const float*)d_in[7];
    const float* W_y     = (const float*)d_in[8];
    const float* W_z     = (const float*)d_in[9];
    const float* W_r     = (const float*)d_in[10];
    const float* W1      = (const float*)d_in[11];
    const float* b1      = (const float*)d_in[12];
    const float* Wg      = (const float*)d_in[13];
    const float* bg      = (const float*)d_in[14];
    const float* W_out   = (const float*)d_in[15];
    const float* b_out   = (const float*)d_in[16];
    float* out = (float*)d_out;

    const int n     = in_sizes[0];
    const int nt    = n / 32;                       // 32-pt tiles
    const int grid  = 256;                          // 1 block per CU; prep once per CU
    const int tiles_per_pass = grid * 16;
    const int niter = (nt + tiles_per_pass - 1) / tiles_per_pass;
    inr_mfma7_kernel<<<dim3(grid), dim3(1024), 0, stream>>>(
        x, y, z, r, noise, W_noise, b_noise, W_x, W_y, W_z, W_r,
        W1, b1, Wg, bg, W_out, b_out, out, nt, niter);
}

// Round 10
// 159.531 us; speedup vs baseline: 1.2628x; 1.0462x over previous
//
#include <hip/hip_runtime.h>

typedef _Float16 f16;
typedef f16  f16x4 __attribute__((ext_vector_type(4)));
typedef f16  f16x8 __attribute__((ext_vector_type(8)));
typedef __fp16 h16x2 __attribute__((ext_vector_type(2)));  // cvt_pkrtz native return type
typedef float f32x4  __attribute__((ext_vector_type(4)));
typedef float f32x16 __attribute__((ext_vector_type(16)));
typedef unsigned int u32;
typedef u32 u32x2 __attribute__((ext_vector_type(2)));
typedef u32 u32x4 __attribute__((ext_vector_type(4)));

#define LOG2E   1.4426950408889634f
#define LN2     0.6931471805599453f
#define C_TANH  2.8853900817779268f    // 2*log2(e)
#define C_SIN   0.15915494309189535f   // 1/(2*pi)
#define C_SIG  -1.4426950408889634f    // -log2(e)
#define C_GAU  -0.7213475204444817f    // -log2(e)/2

// per-node arg prescale baked into W,b at prep: acts 0=tanh,1=elu,2=softplus,3=sin,4=gauss,5=sigmoid
__device__ __constant__ float NSCL[12] = {
    C_TANH, C_TANH, 1.0f, 1.0f, C_SIN, 1.0f, C_SIG, C_TANH, 1.0f, 1.0f, C_SIN, 1.0f
};

__device__ __forceinline__ float frcp(float x){ return __builtin_amdgcn_rcpf(x); }
__device__ __forceinline__ float fexp2(float x){ return __builtin_amdgcn_exp2f(x); }
__device__ __forceinline__ float flog2(float x){ return __builtin_amdgcn_logf(x); }
__device__ __forceinline__ float fsin1(float x){ return __builtin_amdgcn_sinf(x); } // arg in revolutions

// ---------- activations on PRESCALED args (see NSCL) ----------
template<int A> __device__ __forceinline__ float act(float v){
    if constexpr (A == 0){                       // tanh; v = 2log2e*x
        float t = fexp2(v);
        return 1.0f - 2.0f * frcp(1.0f + t);
    } else if constexpr (A == 1){                // elu; v raw
        float e = fexp2(v * LOG2E) - 1.0f;
        return v > 0.0f ? v : e;
    } else if constexpr (A == 2){                // softplus; v raw
        float p = fexp2(-LOG2E * fabsf(v));
        return fmaxf(v, 0.0f) + LN2 * flog2(1.0f + p);
    } else if constexpr (A == 3){                // sin; v = x/(2pi)
        return fsin1(v);
    } else if constexpr (A == 4){                // gauss; v raw
        return fexp2(v * v * C_GAU);
    } else {                                     // sigmoid; v = -log2e*x
        return frcp(1.0f + fexp2(v));
    }
}

__device__ __forceinline__ f16x4 pack4(float a, float b, float c, float d){
    u32x2 u;
    u[0] = __builtin_bit_cast(u32, __builtin_amdgcn_cvt_pkrtz(a, b));
    u[1] = __builtin_bit_cast(u32, __builtin_amdgcn_cvt_pkrtz(c, d));
    return __builtin_bit_cast(f16x4, u);
}
__device__ __forceinline__ f16x8 cat8(f16x4 lo, f16x4 hi){
    u32x2 a = __builtin_bit_cast(u32x2, lo), b = __builtin_bit_cast(u32x2, hi);
    u32x4 u; u[0] = a[0]; u[1] = a[1]; u[2] = b[0]; u[3] = b[1];
    return __builtin_bit_cast(f16x8, u);
}

#define MFMA32(a, b, c) __builtin_amdgcn_mfma_f32_32x32x16_f16((a), (b), (c), 0, 0, 0)

// K-permutation pi: k-slot (kc, 8h+j) holds feature 8*kc + 32*(j>>2) + 4*h + (j&3);
// next node's B-frag[kc] = cat(pk[t=0][g=kc], pk[t=1][g=kc]) -- registers only.
//
// Dual-tile node: ONE A-frag / bias read feeds BOTH tiles (P,Q). NP = #predecessors;
// predecessor sums are formed at point of use (transient) to cap register pressure.
template<int ACTI, int NP>
__device__ __forceinline__ void node32x2(const f16* __restrict__ wr,   // &wfrag[ni][0][0][lane][0]
                                         const float* __restrict__ bs, // &b_s[ni][0] (prescaled)
                                         const int hf4,                // 4*(lane>>5)
                                         const f16x8 A0[2][4], const f16x8 A1[2][4], const f16x8 A2[2][4],
                                         f16x8 OUT[2][4])
{
    f16x4 pkP[2][4], pkQ[2][4];
    #pragma unroll
    for (int t = 0; t < 2; ++t){
        f32x16 aP, aQ;
        #pragma unroll
        for (int g = 0; g < 4; ++g){
            f32x4 bv = *(const f32x4*)(bs + 32 * t + 8 * g + hf4);
            aP[4*g+0] = bv[0]; aP[4*g+1] = bv[1]; aP[4*g+2] = bv[2]; aP[4*g+3] = bv[3];
            aQ[4*g+0] = bv[0]; aQ[4*g+1] = bv[1]; aQ[4*g+2] = bv[2]; aQ[4*g+3] = bv[3];
        }
        #pragma unroll
        for (int kc = 0; kc < 4; ++kc){
            f16x8 Af = *(const f16x8*)(wr + t * 2048 + kc * 512);
            f16x8 bP = A0[0][kc], bQ = A0[1][kc];
            if constexpr (NP >= 2){ bP = bP + A1[0][kc]; bQ = bQ + A1[1][kc]; }
            if constexpr (NP >= 3){ bP = bP + A2[0][kc]; bQ = bQ + A2[1][kc]; }
            aP = MFMA32(Af, bP, aP);
            aQ = MFMA32(Af, bQ, aQ);
        }
        #pragma unroll
        for (int g = 0; g < 4; ++g){
            pkP[t][g] = pack4(act<ACTI>(aP[4*g+0]), act<ACTI>(aP[4*g+1]),
                              act<ACTI>(aP[4*g+2]), act<ACTI>(aP[4*g+3]));
            pkQ[t][g] = pack4(act<ACTI>(aQ[4*g+0]), act<ACTI>(aQ[4*g+1]),
                              act<ACTI>(aQ[4*g+2]), act<ACTI>(aQ[4*g+3]));
        }
    }
    #pragma unroll
    for (int kc = 0; kc < 4; ++kc){
        OUT[0][kc] = cat8(pkP[0][kc], pkP[1][kc]);
        OUT[1][kc] = cat8(pkQ[0][kc], pkQ[1][kc]);
    }
}

__global__ __launch_bounds__(512, 2) void inr_mfma8_kernel(
    const float* __restrict__ gx, const float* __restrict__ gy,
    const float* __restrict__ gz, const float* __restrict__ gr,
    const float* __restrict__ gnoise,
    const float* __restrict__ W_noise, const float* __restrict__ b_noise,
    const float* __restrict__ W_x, const float* __restrict__ W_y,
    const float* __restrict__ W_z, const float* __restrict__ W_r,
    const float* __restrict__ W1, const float* __restrict__ b1,
    const float* __restrict__ Wg, const float* __restrict__ bg,
    const float* __restrict__ W_out, const float* __restrict__ b_out,
    float* __restrict__ out, int nt, int niter)
{
    // ---- LDS ~106 KB, 1 block (8 waves) per CU -> 2 waves/SIMD x dual-stream ----
    __shared__ __align__(16) f16   wfrag[12][2][4][64][8]; // 96 KB  prescaled W^T A-frags, pi-permuted k
    __shared__ __align__(16) f16   nfrag[2][64][8];        //  2 KB  2log2e*W_noise^T
    __shared__ __align__(16) f16   ofrag[4][64][8];        //  4 KB  -log2e*W_out^T (pi, rows>=3 zero)
    __shared__ __align__(16) float b_s[12][64];            //  3 KB  prescaled biases
    __shared__ __align__(16) float wvs[4][64];             //  1 KB  [0]=C_GAU*Wx^2, [1]=2log2e*Wy, [2]=Wz, [3]=Wr
    __shared__ __align__(16) float bns[64];                //  256B  2log2e*b_noise
    __shared__            float bout_s[4];

    const int tid  = threadIdx.x;
    const int lane = tid & 63;
    const int n2   = lane & 31;      // point-in-tile (MFMA col)
    const int hf   = lane >> 5;      // half-wave
    const int hf4  = 4 * hf;

    // ================= PREP: barrier-free direct global->frag (grid=256 -> once per CU) ======
    for (int i = tid; i < 768; i += 512){
        int node = i >> 6, f = i & 63;
        b_s[node][f] = NSCL[node] * ((node == 0) ? b1[f] : bg[(node - 1) * 64 + f]);
    }
    if (tid < 256){
        int vec = tid >> 6, f = tid & 63;
        float v;
        if      (vec == 0){ float w = W_x[f]; v = C_GAU * w * w; }
        else if (vec == 1){ v = C_TANH * W_y[f]; }
        else if (vec == 2){ v = W_z[f]; }
        else              { v = W_r[f]; }
        wvs[vec][f] = v;
    }
    if (tid < 64) bns[tid] = C_TANH * b_noise[tid];
    if (tid < 4)  bout_s[tid] = (tid < 3) ? C_SIG * b_out[tid] : 0.0f;
    if (tid < 128){                                  // nfrag: A[m][k]=2log2e*W_noise[k][m], k=8h+j
        int t = tid >> 6, ln = tid & 63, m = ln & 31, h = ln >> 5;
        f16x8 v;
        #pragma unroll
        for (int j = 0; j < 8; ++j) v[j] = (f16)(C_TANH * W_noise[(8 * h + j) * 64 + 32 * t + m]);
        *(f16x8*)&nfrag[t][ln][0] = v;
    }
    if (tid < 256){                                  // ofrag: A[m][k]=-log2e*W_out[pi][m] (m<3)
        int kc = tid >> 6, ln = tid & 63, m = ln & 31, h = ln >> 5;
        f16x8 v;
        #pragma unroll
        for (int j = 0; j < 8; ++j){
            int kf = 8 * kc + 32 * (j >> 2) + 4 * h + (j & 3);
            v[j] = (m < 3) ? (f16)(C_SIG * W_out[kf * 3 + m]) : (f16)0.0f;
        }
        *(f16x8*)&ofrag[kc][ln][0] = v;
    }
    // big weights: each thread builds one f16x8 A-frag per node straight from global (L2-hot),
    // one ds_write_b128 each, NO intermediate barriers (was 24 barriers via a staging buffer)
    {
        const int t = tid >> 8, kc = (tid >> 6) & 3, ln = tid & 63, m = ln & 31, h = ln >> 5;
        int kfo[8];
        #pragma unroll
        for (int j = 0; j < 8; ++j)
            kfo[j] = (8 * kc + 32 * (j >> 2) + 4 * h + (j & 3)) * 64 + 32 * t + m;
        #pragma unroll
        for (int node = 0; node < 12; ++node){
            const float* Wsrc = (node == 0) ? W1 : (Wg + (node - 1) * 4096);
            const float  scl  = NSCL[node];
            f16x8 v;
            #pragma unroll
            for (int j = 0; j < 8; ++j) v[j] = (f16)(scl * Wsrc[kfo[j]]);
            *(f16x8*)&wfrag[node][t][kc][ln][0] = v;
        }
    }
    __syncthreads();   // single barrier: all fragments complete

    #define WPTR(NI) (&wfrag[NI][0][0][lane][0])
    #define N1(NI, ACTI, A, OUT)        node32x2<ACTI,1>(WPTR(NI), &b_s[NI][0], hf4, A, A, A, OUT)
    #define N2(NI, ACTI, A, B, OUT)     node32x2<ACTI,2>(WPTR(NI), &b_s[NI][0], hf4, A, B, B, OUT)
    #define N3(NI, ACTI, A, B, C, OUT)  node32x2<ACTI,3>(WPTR(NI), &b_s[NI][0], hf4, A, B, C, OUT)

    const int wvid = tid >> 6;       // wave id 0..7

    // ================= MAIN LOOP: 2 tiles (64 pts) per wave per iter =================
    for (int it = 0; it < niter; ++it){
        const int tbase = ((it * gridDim.x + blockIdx.x) * 8 + wvid) * 2;
        if (tbase >= nt) break;

        f16x8 sg[2][4];
        int myp2[2];
        #pragma unroll
        for (int tt = 0; tt < 2; ++tt){
            const int myp = (tbase + tt) * 32 + n2;
            myp2[tt] = myp;
            const float xs = gx[myp], ys = gy[myp], zs = gz[myp], rs = gr[myp];
            const float xs2 = xs * xs;
            f16x8 nb;
            {
                const float4 a4 = *(const float4*)(gnoise + (size_t)myp * 16 + 8 * hf);
                const float4 b4 = *(const float4*)(gnoise + (size_t)myp * 16 + 8 * hf + 4);
                nb = cat8(pack4(a4.x, a4.y, a4.z, a4.w), pack4(b4.x, b4.y, b4.z, b4.w));
            }
            f16x4 pkg[2][4];
            #pragma unroll
            for (int t = 0; t < 2; ++t){
                f32x16 ac;
                #pragma unroll
                for (int i = 0; i < 16; ++i) ac[i] = 0.0f;
                ac = MFMA32(*(const f16x8*)&nfrag[t][lane][0], nb, ac);
                #pragma unroll
                for (int g = 0; g < 4; ++g){
                    const int fb = 32 * t + 8 * g + hf4;
                    const f32x4 wx2 = *(const f32x4*)&wvs[0][fb];   // C_GAU*Wx^2
                    const f32x4 wyt = *(const f32x4*)&wvs[1][fb];   // 2log2e*Wy
                    const f32x4 wz  = *(const f32x4*)&wvs[2][fb];
                    const f32x4 wr_ = *(const f32x4*)&wvs[3][fb];
                    const f32x4 bn  = *(const f32x4*)&bns[fb];      // 2log2e*b_noise
                    float gv[4];
                    #pragma unroll
                    for (int r = 0; r < 4; ++r){
                        float az = zs * wz[r];
                        float velu = az > 0.0f ? az : (fexp2(az * LOG2E) - 1.0f);
                        float vga = fexp2(xs2 * wx2[r]);
                        float vty = 1.0f - 2.0f * frcp(1.0f + fexp2(ys * wyt[r]));
                        float ar = rs * wr_[r];
                        float vsp = fmaxf(ar, 0.0f) + LN2 * flog2(1.0f + fexp2(-LOG2E * fabsf(ar)));
                        float vtp = 1.0f - 2.0f * frcp(1.0f + fexp2(ac[4 * g + r] + bn[r]));
                        gv[r] = fsin1((velu + vga + vty + vsp + vtp) * C_SIN);
                    }
                    pkg[t][g] = pack4(gv[0], gv[1], gv[2], gv[3]);
                }
            }
            #pragma unroll
            for (int kc = 0; kc < 4; ++kc) sg[tt][kc] = cat8(pkg[0][kc], pkg[1][kc]);
        }

        f16x8 h0[2][4], r0[2][4], r1[2][4], r2[2][4], r3[2][4];
        N1(0,  0, sg, h0);                 // h0 = tanh(g @ W1 + b1)
        N1(1,  0, h0, r0);                 // h1 = tanh(h0 W)
        N1(2,  1, r0, r1);                 // h2 = elu(h1 W)
        N2(3,  2, r1, h0, r2);             // h3 = softplus((h2+h0) W)
        N3(4,  3, r2, r0, h0, r3);         // h4 = sin((h3+h1+h0) W)
        N2(5,  4, r3, r1, r0);             // h5 = gauss((h4+h2) W)
        N2(6,  5, r0, r2, r1);             // h6 = sigmoid((h5+h3) W)
        N2(7,  0, r1, r3, r2);             // h7 = tanh((h6+h4) W)
        N3(8,  1, r2, r0, h0, r3);         // h8 = elu((h7+h5+h0) W)
        N2(9,  2, r3, r1, r0);             // h9 = softplus((h8+h6) W)
        N2(10, 3, r0, r2, r1);             // h10= sin((h9+h7) W)
        N2(11, 4, r1, r3, r2);             // h11= gauss((h10+h8) W)

        // ---- output: sigmoid folded into ofrag: out = rcp(1+exp2(om+bout)) ----
        #pragma unroll
        for (int tt = 0; tt < 2; ++tt){
            f32x16 om;
            #pragma unroll
            for (int i = 0; i < 16; ++i) om[i] = 0.0f;
            #pragma unroll
            for (int kc = 0; kc < 4; ++kc)
                om = MFMA32(*(const f16x8*)&ofrag[kc][lane][0], r2[tt][kc], om);
            if (hf == 0){
                #pragma unroll
                for (int r = 0; r < 3; ++r)
                    out[(size_t)myp2[tt] * 3 + r] = frcp(1.0f + fexp2(om[r] + bout_s[r]));
            }
        }
    }
    #undef N1
    #undef N2
    #undef N3
    #undef WPTR
}

extern "C" void kernel_launch(void* const* d_in, const int* in_sizes, int n_in,
                              void* d_out, int out_size, void* d_ws, size_t ws_size,
                              hipStream_t stream)
{
    const float* x       = (const float*)d_in[0];
    const float* y       = (const float*)d_in[1];
    const float* z       = (const float*)d_in[2];
    const float* r       = (const float*)d_in[3];
    const float* noise   = (const float*)d_in[4];
    const float* W_noise = (const float*)d_in[5];
    const float* b_noise = (const float*)d_in[6];
    const float* W_x     = (const float*)d_in[7];
    const float* W_y     = (const float*)d_in[8];
    const float* W_z     = (const float*)d_in[9];
    const float* W_r     = (const float*)d_in[10];
    const float* W1      = (const float*)d_in[11];
    const float* b1      = (const float*)d_in[12];
    const float* Wg      = (const float*)d_in[13];
    const float* bg      = (const float*)d_in[14];
    const float* W_out   = (const float*)d_in[15];
    const float* b_out   = (const float*)d_in[16];
    float* out = (float*)d_out;

    const int n     = in_sizes[0];
    const int nt    = n / 32;                       // 32-pt tiles (8192)
    const int grid  = 256;                          // 1 block per CU; prep once per CU
    const int tiles_per_pass = grid * 8 * 2;        // 8 waves x 2 tiles
    const int niter = (nt + tiles_per_pass - 1) / tiles_per_pass;
    inr_mfma8_kernel<<<dim3(grid), dim3(512), 0, stream>>>(
        x, y, z, r, noise, W_noise, b_noise, W_x, W_y, W_z, W_r,
        W1, b1, Wg, bg, W_out, b_out, out, nt, niter);
}